// Round 5
// baseline (709.950 us; speedup 1.0000x reference)
//
#include <hip/hip_runtime.h>

// ---------------- types / helpers ----------------
typedef short v8s __attribute__((ext_vector_type(8)));
typedef float v4f __attribute__((ext_vector_type(4)));

#define MFMA16(a, b, c) __builtin_amdgcn_mfma_f32_16x16x32_bf16(a, b, c, 0, 0, 0)

__device__ __forceinline__ unsigned short f2b(float f) {
  union { float f; unsigned int i; } v;
  v.f = f;
  unsigned int x = v.i;
  return (unsigned short)((x + 0x7fffu + ((x >> 16) & 1u)) >> 16);
}
// load 8 consecutive fp32 from global, convert to bf16 fragment
__device__ __forceinline__ v8s ldf8(const float* p) {
  float4 a = *(const float4*)p;
  float4 b = *(const float4*)(p + 4);
  union { v8s v; unsigned short u[8]; } r;
  r.u[0] = f2b(a.x); r.u[1] = f2b(a.y); r.u[2] = f2b(a.z); r.u[3] = f2b(a.w);
  r.u[4] = f2b(b.x); r.u[5] = f2b(b.y); r.u[6] = f2b(b.z); r.u[7] = f2b(b.w);
  return r.v;
}
// load 16 bytes (8 bf16) via two 8B LDS reads (rows may be only 8B-aligned)
__device__ __forceinline__ v8s ld16u(const unsigned short* p) {
  union { v8s v; ushort4 h[2]; } u;
  u.h[0] = *(const ushort4*)(p);
  u.h[1] = *(const ushort4*)(p + 4);
  return u.v;
}
// stage a 128x128 fp32 global tile into swizzled bf16 LDS (16B granules)
__device__ __forceinline__ void stage128(const float* __restrict__ src,
                                         unsigned short* __restrict__ xs, int tid) {
  for (int it = 0; it < 8; ++it) {
    int gl = tid + 256 * it;           // 0..2047
    int row = gl >> 4, g = gl & 15;    // row 0..127, 16B-granule 0..15
    const float4* s = (const float4*)(src + row * 128 + g * 8);
    float4 a = s[0], b = s[1];
    union { int4 v; unsigned short u[8]; } pk;
    pk.u[0] = f2b(a.x); pk.u[1] = f2b(a.y); pk.u[2] = f2b(a.z); pk.u[3] = f2b(a.w);
    pk.u[4] = f2b(b.x); pk.u[5] = f2b(b.y); pk.u[6] = f2b(b.z); pk.u[7] = f2b(b.w);
    *(int4*)(xs + row * 128 + ((g ^ (row & 15)) << 3)) = pk.v;
  }
}

#define SCALE 0.17677669529663687f

// ---------------- K1: fused qkv + attention per (b, h) ----------------
// grid: 8192 blocks of 256 threads (4 waves). idx -> (wgrp, h, bgrp) so that
// blocks sharing mask[wgrp]/sp[wgrp]/rpi/btab are temporally adjacent (L2).
// Zero workspace: O intermediate goes to d_out (fp32); proj rewrites in place.
__global__ __launch_bounds__(256, 2)
void attn_kernel(const float* __restrict__ xg,
                 const float* __restrict__ wq,
                 const float* __restrict__ bq,
                 const float* __restrict__ maskg,
                 const float* __restrict__ spg,
                 const int* __restrict__ rpi,
                 const float* __restrict__ btab,
                 float* __restrict__ o_ws) {
  // LDS: [0,33792) P (128x132) aliased with X (128x128 swizzled, 32KB)
  //      [33792,43008) Q (128x36)   [43008,52224) K (128x36)
  //      [52224,60672) V^T (32x132)
  __shared__ alignas(16) unsigned char smem[60672];
  unsigned short* ps  = (unsigned short*)smem;
  unsigned short* xs  = (unsigned short*)smem;
  unsigned short* qs  = (unsigned short*)(smem + 33792);
  unsigned short* kss = (unsigned short*)(smem + 43008);
  unsigned short* vs  = (unsigned short*)(smem + 52224);

  const int tid = threadIdx.x;
  const int wv = tid >> 6;
  const int lane = tid & 63;
  const int qd = lane >> 4;   // quarter 0..3
  const int t16 = lane & 15;

  const int idx = blockIdx.x;
  const int wgrp = idx >> 5;          // 0..255 : mask index
  const int rem = idx & 31;
  const int h = rem >> 3;             // head
  const int b = (rem & 7) * 256 + wgrp;  // window (b % 256 == wgrp)

  // ---- stage x[b] (128x128 fp32 -> bf16 LDS, XOR swizzle) ----
  stage128(xg + (size_t)b * 16384, xs, tid);
  __syncthreads();

  // ---- phase 1: qkv slices for this head ----
  v8s bx[2][4];
  for (int nt = 0; nt < 2; ++nt)
    for (int ks = 0; ks < 4; ++ks) {
      int n = 32 * wv + nt * 16 + t16;
      int g = ks * 4 + qd;
      bx[nt][ks] = *(const v8s*)(xs + n * 128 + ((g ^ (n & 15)) << 3));
    }

  // q,k via out^T = W @ X^T : rows j (0..63: q then k), cols n (wave strip 32)
  v4f accqk[4][2];
  for (int jt = 0; jt < 4; ++jt)
    for (int nt = 0; nt < 2; ++nt) accqk[jt][nt] = v4f{0.f, 0.f, 0.f, 0.f};
  for (int jt = 0; jt < 4; ++jt) {
    int wbase = (jt < 2) ? (h * 32 + jt * 16) : (128 + h * 32 + (jt - 2) * 16);
    for (int ks = 0; ks < 4; ++ks) {
      v8s a = ldf8(wq + (wbase + t16) * 128 + ks * 32 + 8 * qd);
      for (int nt = 0; nt < 2; ++nt)
        accqk[jt][nt] = MFMA16(a, bx[nt][ks], accqk[jt][nt]);
    }
  }
  // v via out = X @ Wv^T : rows n (strip 32), cols d (32)
  v4f accv[2][2];
  for (int rt = 0; rt < 2; ++rt)
    for (int ct = 0; ct < 2; ++ct) accv[rt][ct] = v4f{0.f, 0.f, 0.f, 0.f};
  for (int ct = 0; ct < 2; ++ct)
    for (int ks = 0; ks < 4; ++ks) {
      v8s bw = ldf8(wq + (256 + h * 32 + ct * 16 + t16) * 128 + ks * 32 + 8 * qd);
      for (int rt = 0; rt < 2; ++rt)
        accv[rt][ct] = MFMA16(bx[rt][ks], bw, accv[rt][ct]);
    }

  // epilogue q,k: C layout rows are 4 consecutive j -> packed 8B LDS stores
  for (int jt = 0; jt < 4; ++jt) {
    bool isq = jt < 2;
    for (int nt = 0; nt < 2; ++nt) {
      int n = 32 * wv + nt * 16 + t16;
      float vv[4];
      for (int r = 0; r < 4; ++r) {
        int jl = jt * 16 + 4 * qd + r;
        int wrow = isq ? (h * 32 + jl) : (128 + h * 32 + (jl - 32));
        float val = accqk[jt][nt][r] + bq[wrow];
        if (isq) val *= SCALE;
        vv[r] = val;
      }
      ushort4 pk;
      pk.x = f2b(vv[0]); pk.y = f2b(vv[1]); pk.z = f2b(vv[2]); pk.w = f2b(vv[3]);
      unsigned short* dst = isq ? qs : kss;
      int dbase = (isq ? jt : (jt - 2)) * 16 + 4 * qd;
      *(ushort4*)(dst + n * 36 + dbase) = pk;
    }
  }
  // epilogue v: store transposed V^T[d][n], 4 consecutive n per reg -> 8B stores
  for (int ct = 0; ct < 2; ++ct) {
    int d = ct * 16 + t16;
    float bv = bq[256 + h * 32 + d];
    for (int rt = 0; rt < 2; ++rt) {
      ushort4 pk;
      pk.x = f2b(accv[rt][ct][0] + bv);
      pk.y = f2b(accv[rt][ct][1] + bv);
      pk.z = f2b(accv[rt][ct][2] + bv);
      pk.w = f2b(accv[rt][ct][3] + bv);
      *(ushort4*)(vs + d * 132 + 32 * wv + rt * 16 + 4 * qd) = pk;
    }
  }
  __syncthreads();

  // ---- phase 2: S = Q K^T (+ mask + sp_mask + rpb), softmax -> P (bf16) ----
  v8s aq[2];
  for (int rt = 0; rt < 2; ++rt) {
    int n = 32 * wv + rt * 16 + t16;
    aq[rt] = ld16u(qs + n * 36 + 8 * qd);
  }
  v4f sa[2][8];
  const v4f zero4 = {0.f, 0.f, 0.f, 0.f};
  for (int ct = 0; ct < 8; ++ct) {
    int key = ct * 16 + t16;
    v8s bk = ld16u(kss + key * 36 + 8 * qd);
    for (int rt = 0; rt < 2; ++rt)
      sa[rt][ct] = MFMA16(aq[rt], bk, zero4);
  }
  const float* mk = maskg + (size_t)wgrp * 16384;
  const float* sk = spg + (size_t)wgrp * 16384;
  for (int rt = 0; rt < 2; ++rt)
    for (int r = 0; r < 4; ++r) {
      int n = 32 * wv + rt * 16 + 4 * qd + r;
      const float* mr = mk + n * 128;
      const float* sr = sk + n * 128;
      const int* ir = rpi + n * 128;
      for (int ct = 0; ct < 8; ++ct) {
        int m = ct * 16 + t16;
        sa[rt][ct][r] += mr[m] + sr[m] + btab[ir[m] * 4 + h];
      }
    }
  float pmax[2][4], pinv[2][4];
  for (int rt = 0; rt < 2; ++rt)
    for (int r = 0; r < 4; ++r) {
      float m0 = sa[rt][0][r];
      for (int ct = 1; ct < 8; ++ct) m0 = fmaxf(m0, sa[rt][ct][r]);
      m0 = fmaxf(m0, __shfl_xor(m0, 1));
      m0 = fmaxf(m0, __shfl_xor(m0, 2));
      m0 = fmaxf(m0, __shfl_xor(m0, 4));
      m0 = fmaxf(m0, __shfl_xor(m0, 8));
      pmax[rt][r] = m0;
    }
  for (int rt = 0; rt < 2; ++rt)
    for (int ct = 0; ct < 8; ++ct)
      for (int r = 0; r < 4; ++r)
        sa[rt][ct][r] = __expf(sa[rt][ct][r] - pmax[rt][r]);
  for (int rt = 0; rt < 2; ++rt)
    for (int r = 0; r < 4; ++r) {
      float s0 = 0.f;
      for (int ct = 0; ct < 8; ++ct) s0 += sa[rt][ct][r];
      s0 += __shfl_xor(s0, 1);
      s0 += __shfl_xor(s0, 2);
      s0 += __shfl_xor(s0, 4);
      s0 += __shfl_xor(s0, 8);
      pinv[rt][r] = 1.0f / s0;
    }
  // write normalized P (bf16)
  for (int rt = 0; rt < 2; ++rt)
    for (int r = 0; r < 4; ++r) {
      int n = 32 * wv + rt * 16 + 4 * qd + r;
      for (int ct = 0; ct < 8; ++ct)
        ps[n * 132 + ct * 16 + t16] = f2b(sa[rt][ct][r] * pinv[rt][r]);
    }
  __syncthreads();

  // ---- phase 3: O^T = V^T P^T ; write O[b][n][h*32+d] (float4 stores) ----
  v8s av[2][4];
  for (int rt = 0; rt < 2; ++rt)
    for (int ks = 0; ks < 4; ++ks) {
      int d = rt * 16 + t16;
      av[rt][ks] = ld16u(vs + d * 132 + ks * 32 + 8 * qd);
    }
  v4f oa[2][2];
  for (int rt = 0; rt < 2; ++rt)
    for (int ct = 0; ct < 2; ++ct) oa[rt][ct] = v4f{0.f, 0.f, 0.f, 0.f};
  for (int ct = 0; ct < 2; ++ct) {
    int n = 32 * wv + ct * 16 + t16;
    for (int ks = 0; ks < 4; ++ks) {
      v8s bp = ld16u(ps + n * 132 + ks * 32 + 8 * qd);
      for (int rt = 0; rt < 2; ++rt)
        oa[rt][ct] = MFMA16(av[rt][ks], bp, oa[rt][ct]);
    }
  }
  for (int rt = 0; rt < 2; ++rt)
    for (int ct = 0; ct < 2; ++ct) {
      int n = 32 * wv + ct * 16 + t16;
      int cbase = h * 32 + rt * 16 + 4 * qd;
      float4 pk;
      pk.x = oa[rt][ct][0];
      pk.y = oa[rt][ct][1];
      pk.z = oa[rt][ct][2];
      pk.w = oa[rt][ct][3];
      *(float4*)(o_ws + ((size_t)(b * 128 + n)) * 128 + cbase) = pk;
    }
}

// ---------------- K2: out = O @ w_proj^T + b_proj (IN PLACE on d_out) -------
// computed as out^T = Wp @ O^T so C-fragments give 4 consecutive channels
__global__ __launch_bounds__(256, 2)
void proj_kernel(const float* __restrict__ wp,
                 const float* __restrict__ bpj,
                 float* __restrict__ out) {
  __shared__ alignas(16) unsigned short os[128 * 128];  // bf16 O tile, swizzled
  const int tid = threadIdx.x;
  const int wv = tid >> 6;
  const int lane = tid & 63;
  const int qd = lane >> 4;
  const int t16 = lane & 15;
  const size_t row0 = (size_t)blockIdx.x * 128;

  stage128(out + row0 * 128, os, tid);   // all reads of out rows before barrier
  __syncthreads();

  // B-frags: token rows n from LDS (k = input channel)
  v8s bo[2][4];
  for (int ct = 0; ct < 2; ++ct)
    for (int ks = 0; ks < 4; ++ks) {
      int n = 32 * wv + ct * 16 + t16;
      int g = ks * 4 + qd;
      bo[ct][ks] = *(const v8s*)(os + n * 128 + ((g ^ (n & 15)) << 3));
    }
  v4f acc[8][2];
  for (int rt = 0; rt < 8; ++rt)
    for (int ct = 0; ct < 2; ++ct) acc[rt][ct] = v4f{0.f, 0.f, 0.f, 0.f};
  for (int rt = 0; rt < 8; ++rt)
    for (int ks = 0; ks < 4; ++ks) {
      v8s a = ldf8(wp + (rt * 16 + t16) * 128 + ks * 32 + 8 * qd);
      for (int ct = 0; ct < 2; ++ct)
        acc[rt][ct] = MFMA16(a, bo[ct][ks], acc[rt][ct]);
    }
  for (int rt = 0; rt < 8; ++rt) {
    float4 bj = *(const float4*)(bpj + rt * 16 + 4 * qd);
    for (int ct = 0; ct < 2; ++ct) {
      int n = 32 * wv + ct * 16 + t16;
      float4 pk;
      pk.x = acc[rt][ct][0] + bj.x;
      pk.y = acc[rt][ct][1] + bj.y;
      pk.z = acc[rt][ct][2] + bj.z;
      pk.w = acc[rt][ct][3] + bj.w;
      *(float4*)(out + (row0 + n) * 128 + rt * 16 + 4 * qd) = pk;
    }
  }
}

// ---------------- launch ----------------
extern "C" void kernel_launch(void* const* d_in, const int* in_sizes, int n_in,
                              void* d_out, int out_size, void* d_ws, size_t ws_size,
                              hipStream_t stream) {
  (void)in_sizes; (void)n_in; (void)out_size; (void)d_ws; (void)ws_size;
  const float* xg   = (const float*)d_in[0];
  const int*   rpi  = (const int*)d_in[1];
  const float* mask = (const float*)d_in[2];
  const float* sp   = (const float*)d_in[3];
  const float* wq   = (const float*)d_in[4];
  const float* bq   = (const float*)d_in[5];
  const float* btab = (const float*)d_in[6];
  const float* wp   = (const float*)d_in[7];
  const float* bpj  = (const float*)d_in[8];
  float* out = (float*)d_out;

  // Zero workspace use: O intermediate lives in d_out; proj projects in place.
  attn_kernel<<<8192, 256, 0, stream>>>(xg, wq, bq, mask, sp, rpi, btab, out);
  proj_kernel<<<2048, 256, 0, stream>>>(wp, bpj, out);
}